// Round 1
// baseline (321.375 us; speedup 1.0000x reference)
//
#include <hip/hip_runtime.h>
#include <math.h>

// Problem constants (from the reference):
//   B=262144 items, W=8 context window, K=3 negatives, V=100000 vocab, E=128 dim
#define B_ITEMS 262144
#define W_CTX   8
#define K_NEG   3
#define E_DIM   128

// Numerically stable log-sigmoid: log_sigmoid(x) = min(x,0) - log1p(exp(-|x|))
__device__ __forceinline__ float log_sigmoid_f(float x) {
    return fminf(x, 0.0f) - log1pf(expf(-fabsf(x)));
}

__global__ void init_out_kernel(float* out) {
    if (threadIdx.x == 0 && blockIdx.x == 0) out[0] = 0.0f;
}

// One wave (64 lanes) per item; lane l owns E-elements [2l, 2l+1] as float2.
// Grid-stride over items; per-wave accumulator; block reduce; 1 atomic/block.
__global__ void __launch_bounds__(256, 8) cbow_neg_loss_kernel(
    const int*   __restrict__ targets,     // [B]
    const int*   __restrict__ contexts,    // [B, W]
    const int*   __restrict__ negsamples,  // [B, K]
    const float* __restrict__ target_W,    // [V, E]
    const float* __restrict__ context_W,   // [V, E]
    float*       __restrict__ out)         // [1]
{
    const int lane        = threadIdx.x & 63;
    const int wave_in_blk = threadIdx.x >> 6;
    const int waves_blk   = blockDim.x >> 6;
    const int gwave       = blockIdx.x * waves_blk + wave_in_blk;
    const int nwaves      = gridDim.x * waves_blk;

    const int e_off = lane * 2;  // this lane's float2 offset within a row

    float local_sum = 0.0f;  // sum of per_item = logsig(pos) + logsig(neg)

    for (int b = gwave; b < B_ITEMS; b += nwaves) {
        // ---- load all 12 indices first (wave-uniform broadcast loads) ----
        const int t = targets[b];
        int cidx[W_CTX];
        #pragma unroll
        for (int w = 0; w < W_CTX; ++w) cidx[w] = contexts[b * W_CTX + w];
        int nidx[K_NEG];
        #pragma unroll
        for (int k = 0; k < K_NEG; ++k) nidx[k] = negsamples[b * K_NEG + k];

        // ---- gather rows: 12 coalesced 512B wave loads, issued back-to-back ----
        const float2 tg = *reinterpret_cast<const float2*>(
            &target_W[(size_t)t * E_DIM + e_off]);

        float2 cs = make_float2(0.0f, 0.0f);
        #pragma unroll
        for (int w = 0; w < W_CTX; ++w) {
            const float2 c = *reinterpret_cast<const float2*>(
                &context_W[(size_t)cidx[w] * E_DIM + e_off]);
            cs.x += c.x; cs.y += c.y;
        }

        float2 ns = make_float2(0.0f, 0.0f);
        #pragma unroll
        for (int k = 0; k < K_NEG; ++k) {
            const float2 c = *reinterpret_cast<const float2*>(
                &context_W[(size_t)nidx[k] * E_DIM + e_off]);
            ns.x += c.x; ns.y += c.y;
        }

        // ---- per-lane partial dots ----
        float pos = (cs.x * tg.x + cs.y * tg.y) * (1.0f / W_CTX);  // mean over W
        float neg = -(ns.x * tg.x + ns.y * tg.y);                  // -sum_k dot

        // ---- 64-lane butterfly reduction (both scores together) ----
        #pragma unroll
        for (int off = 32; off > 0; off >>= 1) {
            pos += __shfl_xor(pos, off, 64);
            neg += __shfl_xor(neg, off, 64);
        }

        if (lane == 0) {
            local_sum += log_sigmoid_f(pos) + log_sigmoid_f(neg);
        }
    }

    // ---- block reduction: one partial per wave -> LDS -> one atomic/block ----
    __shared__ float sm[8];  // up to 8 waves per 512-thread block; we use 4
    if (lane == 0) sm[wave_in_blk] = local_sum;
    __syncthreads();
    if (threadIdx.x == 0) {
        float s = 0.0f;
        for (int w = 0; w < waves_blk; ++w) s += sm[w];
        // loss = -(sum per_item) / B  -> fold sign & scale into the atomic
        atomicAdd(out, s * (-1.0f / (float)B_ITEMS));
    }
}

extern "C" void kernel_launch(void* const* d_in, const int* in_sizes, int n_in,
                              void* d_out, int out_size, void* d_ws, size_t ws_size,
                              hipStream_t stream) {
    const int*   targets    = (const int*)  d_in[0];
    const int*   contexts   = (const int*)  d_in[1];
    const int*   negsamples = (const int*)  d_in[2];
    const float* target_W   = (const float*)d_in[3];
    const float* context_W  = (const float*)d_in[4];
    float*       out        = (float*)      d_out;

    // d_out is re-poisoned (0xAA) before every timed replay -> zero it first.
    init_out_kernel<<<1, 64, 0, stream>>>(out);

    // 2048 blocks x 256 threads = 8192 waves; 32 items/wave; 8 blocks/CU.
    const int threads = 256;
    const int blocks  = 2048;
    cbow_neg_loss_kernel<<<blocks, threads, 0, stream>>>(
        targets, contexts, negsamples, target_W, context_W, out);
}

// Round 2
// 262.763 us; speedup vs baseline: 1.2231x; 1.2231x over previous
//
#include <hip/hip_runtime.h>
#include <math.h>
#include <stdint.h>

// Problem constants (from the reference):
//   B=262144 items, W=8 context window, K=3 negatives, V=100000 vocab, E=128 dim
#define B_ITEMS 262144
#define W_CTX   8
#define K_NEG   3
#define E_DIM   128
#define V_VOCAB 100000

// ws requirement for the bf16 copy of context_W: 100000*128*2 bytes
#define CTX_BF16_BYTES ((size_t)V_VOCAB * E_DIM * 2)

// Numerically stable log-sigmoid: log_sigmoid(x) = min(x,0) - log1p(exp(-|x|))
__device__ __forceinline__ float log_sigmoid_f(float x) {
    return fminf(x, 0.0f) - log1pf(expf(-fabsf(x)));
}

// round-to-nearest-even f32 -> bf16 bits
__device__ __forceinline__ uint32_t bf16_rn_bits(float x) {
    uint32_t u = __float_as_uint(x);
    return (u + 0x7fffu + ((u >> 16) & 1u)) >> 16;
}

__global__ void init_out_kernel(float* out) {
    if (threadIdx.x == 0 && blockIdx.x == 0) out[0] = 0.0f;
}

// context_W (f32, V*E) -> packed bf16 pairs in d_ws. 77 MB of streaming traffic.
__global__ void __launch_bounds__(256) convert_ctx_bf16_kernel(
    const float* __restrict__ src, uint2* __restrict__ dst, int n4)
{
    int i = blockIdx.x * blockDim.x + threadIdx.x;
    const int stride = gridDim.x * blockDim.x;
    const float4* s4 = reinterpret_cast<const float4*>(src);
    for (; i < n4; i += stride) {
        float4 v = s4[i];
        uint2 o;
        o.x = bf16_rn_bits(v.x) | (bf16_rn_bits(v.y) << 16);
        o.y = bf16_rn_bits(v.z) | (bf16_rn_bits(v.w) << 16);
        dst[i] = o;
    }
}

// One wave per 32 CONSECUTIVE items. Lane l owns E-elements {2l, 2l+1}.
// Indices: 3 masked loads (lanes 0..11) + v_readlane -> SGPR-uniform gather bases.
template <bool BF16CTX>
__global__ void __launch_bounds__(256, 8) cbow_kernel(
    const int*      __restrict__ targets,    // [B]
    const int*      __restrict__ contexts,   // [B, W]
    const int*      __restrict__ negsamples, // [B, K]
    const float*    __restrict__ target_W,   // [V, E] f32
    const float*    __restrict__ ctxW_f32,   // [V, E] f32 (fallback path)
    const uint32_t* __restrict__ ctxW_bf16,  // [V, E/2] packed bf16 pairs
    float*          __restrict__ out)        // [1]
{
    const int lane        = threadIdx.x & 63;
    const int wave_in_blk = threadIdx.x >> 6;
    const int wid         = blockIdx.x * (blockDim.x >> 6) + wave_in_blk;
    // 8192 waves x 32 items = 262144, exact.
    const int b0 = wid * 32;

    float local_sum = 0.0f;

    for (int i = 0; i < 32; ++i) {
        const int b = b0 + i;

        // ---- 3 masked index loads, lanes 0..11 participate ----
        int myidx = 0;
        if (lane < W_CTX)               myidx = contexts[b * W_CTX + lane];
        else if (lane < W_CTX + K_NEG)  myidx = negsamples[b * K_NEG + (lane - W_CTX)];
        else if (lane == W_CTX + K_NEG) myidx = targets[b];

        // ---- broadcast to SGPRs ----
        int cidx[W_CTX], nidx[K_NEG];
        #pragma unroll
        for (int w = 0; w < W_CTX; ++w)
            cidx[w] = __builtin_amdgcn_readlane(myidx, w);
        #pragma unroll
        for (int k = 0; k < K_NEG; ++k)
            nidx[k] = __builtin_amdgcn_readlane(myidx, W_CTX + k);
        const int t = __builtin_amdgcn_readlane(myidx, W_CTX + K_NEG);

        // ---- target row: f32, float2 per lane (512B coalesced) ----
        const float2 tg = *reinterpret_cast<const float2*>(
            &target_W[(size_t)t * E_DIM + lane * 2]);

        float csx = 0.0f, csy = 0.0f;   // sum of context rows (this lane's 2 elems)
        float nsx = 0.0f, nsy = 0.0f;   // sum of negative rows

        if (BF16CTX) {
            #pragma unroll
            for (int w = 0; w < W_CTX; ++w) {
                const uint32_t v = ctxW_bf16[(size_t)cidx[w] * (E_DIM / 2) + lane];
                csx += __uint_as_float(v << 16);
                csy += __uint_as_float(v & 0xffff0000u);
            }
            #pragma unroll
            for (int k = 0; k < K_NEG; ++k) {
                const uint32_t v = ctxW_bf16[(size_t)nidx[k] * (E_DIM / 2) + lane];
                nsx += __uint_as_float(v << 16);
                nsy += __uint_as_float(v & 0xffff0000u);
            }
        } else {
            #pragma unroll
            for (int w = 0; w < W_CTX; ++w) {
                const float2 c = *reinterpret_cast<const float2*>(
                    &ctxW_f32[(size_t)cidx[w] * E_DIM + lane * 2]);
                csx += c.x; csy += c.y;
            }
            #pragma unroll
            for (int k = 0; k < K_NEG; ++k) {
                const float2 c = *reinterpret_cast<const float2*>(
                    &ctxW_f32[(size_t)nidx[k] * E_DIM + lane * 2]);
                nsx += c.x; nsy += c.y;
            }
        }

        // ---- per-lane partial dots ----
        float pos = (csx * tg.x + csy * tg.y) * (1.0f / W_CTX);
        float neg = -(nsx * tg.x + nsy * tg.y);

        // ---- 64-lane butterfly reduction ----
        #pragma unroll
        for (int off = 32; off > 0; off >>= 1) {
            pos += __shfl_xor(pos, off, 64);
            neg += __shfl_xor(neg, off, 64);
        }

        if (lane == 0)
            local_sum += log_sigmoid_f(pos) + log_sigmoid_f(neg);
    }

    // ---- block reduction: one partial per wave -> LDS -> one atomic/block ----
    __shared__ float sm[4];
    if (lane == 0) sm[wave_in_blk] = local_sum;
    __syncthreads();
    if (threadIdx.x == 0) {
        float s = sm[0] + sm[1] + sm[2] + sm[3];
        atomicAdd(out, s * (-1.0f / (float)B_ITEMS));
    }
}

extern "C" void kernel_launch(void* const* d_in, const int* in_sizes, int n_in,
                              void* d_out, int out_size, void* d_ws, size_t ws_size,
                              hipStream_t stream) {
    const int*   targets    = (const int*)  d_in[0];
    const int*   contexts   = (const int*)  d_in[1];
    const int*   negsamples = (const int*)  d_in[2];
    const float* target_W   = (const float*)d_in[3];
    const float* context_W  = (const float*)d_in[4];
    float*       out        = (float*)      d_out;

    // d_out is re-poisoned (0xAA) before every timed replay -> zero it first.
    init_out_kernel<<<1, 64, 0, stream>>>(out);

    const bool use_bf16 = (ws_size >= CTX_BF16_BYTES);

    if (use_bf16) {
        uint2* ctx_bf16 = (uint2*)d_ws;
        const int n4 = V_VOCAB * E_DIM / 4;  // float4 chunks
        convert_ctx_bf16_kernel<<<2048, 256, 0, stream>>>(context_W, ctx_bf16, n4);
        cbow_kernel<true><<<2048, 256, 0, stream>>>(
            targets, contexts, negsamples, target_W, context_W,
            (const uint32_t*)d_ws, out);
    } else {
        cbow_kernel<false><<<2048, 256, 0, stream>>>(
            targets, contexts, negsamples, target_W, context_W,
            (const uint32_t*)nullptr, out);
    }
}

// Round 3
// 240.931 us; speedup vs baseline: 1.3339x; 1.0906x over previous
//
#include <hip/hip_runtime.h>
#include <math.h>
#include <stdint.h>

// Problem constants (from the reference):
//   B=262144 items, W=8 context window, K=3 negatives, V=100000 vocab, E=128 dim
#define B_ITEMS 262144
#define W_CTX   8
#define K_NEG   3
#define E_DIM   128
#define V_VOCAB 100000

typedef _Float16 half_t;
typedef __attribute__((ext_vector_type(2))) _Float16 half2_t;

// 25.6 MB per f16 table copy
#define F16_TABLE_BYTES ((size_t)V_VOCAB * E_DIM * 2)

// Numerically stable log-sigmoid: log_sigmoid(x) = min(x,0) - log1p(exp(-|x|))
__device__ __forceinline__ float log_sigmoid_f(float x) {
    return fminf(x, 0.0f) - log1pf(expf(-fabsf(x)));
}

// f16x2 pair dot with f32 accumulate: c + a.x*b.x + a.y*b.y in ONE VALU op
__device__ __forceinline__ float dot2acc(half2_t a, half2_t b, float c) {
#if __has_builtin(__builtin_amdgcn_fdot2)
    return __builtin_amdgcn_fdot2(a, b, c, false);
#else
    return c + (float)a[0] * (float)b[0] + (float)a[1] * (float)b[1];
#endif
}

__device__ __forceinline__ half2_t h2_from_u32(uint32_t u) {
    return __builtin_bit_cast(half2_t, u);
}
__device__ __forceinline__ uint32_t u32_from_h2(half2_t h) {
    return __builtin_bit_cast(uint32_t, h);
}

__global__ void init_out_kernel(float* out) {
    if (threadIdx.x == 0 && blockIdx.x == 0) out[0] = 0.0f;
}

// Convert BOTH tables f32 -> packed f16 pairs in one pass (RN via compiler cast).
__global__ void __launch_bounds__(256) convert_f16_both_kernel(
    const float* __restrict__ srcA, uint2* __restrict__ dstA,
    const float* __restrict__ srcB, uint2* __restrict__ dstB, int n4)
{
    int i = blockIdx.x * blockDim.x + threadIdx.x;
    const int stride = gridDim.x * blockDim.x;
    const float4* a4 = reinterpret_cast<const float4*>(srcA);
    const float4* b4 = reinterpret_cast<const float4*>(srcB);
    for (; i < n4; i += stride) {
        float4 va = a4[i];
        uint2 oa;
        oa.x = u32_from_h2(half2_t{(half_t)va.x, (half_t)va.y});
        oa.y = u32_from_h2(half2_t{(half_t)va.z, (half_t)va.w});
        dstA[i] = oa;
        if (dstB) {
            float4 vb = b4[i];
            uint2 ob;
            ob.x = u32_from_h2(half2_t{(half_t)vb.x, (half_t)vb.y});
            ob.y = u32_from_h2(half2_t{(half_t)vb.z, (half_t)vb.w});
            dstB[i] = ob;
        }
    }
}

// 4 items per wave: group g = lanes [16g,16g+15]; lane owns 8 elems (16B f16).
// Each group loads its own item's indices (same-address broadcast within group),
// gathers rows with 32-bit offsets off an SGPR base, and does per-row f16 pair
// dots straight against the target fragment. 16-lane butterfly = allreduce, so
// logsig runs on all lanes with no divergence.
template <bool CTX16, bool TGT16>
__global__ void __launch_bounds__(256, 8) cbow_kernel(
    const int*      __restrict__ targets,     // [B]
    const int*      __restrict__ contexts,    // [B, W]
    const int*      __restrict__ negsamples,  // [B, K]
    const float*    __restrict__ target_W,    // [V, E] f32
    const float*    __restrict__ context_W,   // [V, E] f32 (fallback)
    const uint32_t* __restrict__ ctx16,       // [V, E/2] packed f16 pairs
    const uint32_t* __restrict__ tgt16,       // [V, E/2] packed f16 pairs
    float*          __restrict__ out)         // [1]
{
    const int lane = threadIdx.x & 63;
    const int wib  = threadIdx.x >> 6;
    const int wid  = blockIdx.x * (blockDim.x >> 6) + wib;
    const int grp  = lane >> 4;          // which item of the quad
    const int sub  = lane & 15;          // 8-elem chunk within the row
    const uint32_t sub16 = (uint32_t)sub * 16;  // byte offset (f16 rows, 256B)

    const char* ctxb = reinterpret_cast<const char*>(ctx16);
    const char* tgtb = reinterpret_cast<const char*>(tgt16);

    float wave_sum = 0.0f;  // identical across lanes of a group

    // 8 quads per wave * 4 items = 32 items/wave; 8192 waves total -> exact.
    for (int i = 0; i < 8; ++i) {
        const int b = (wid * 8 + i) * 4 + grp;

        // ---- indices: broadcast loads within each 16-lane group ----
        const int4 c0 = *reinterpret_cast<const int4*>(&contexts[b * W_CTX]);
        const int4 c1 = *reinterpret_cast<const int4*>(&contexts[b * W_CTX + 4]);
        const int  n0 = negsamples[b * K_NEG + 0];
        const int  n1 = negsamples[b * K_NEG + 1];
        const int  n2 = negsamples[b * K_NEG + 2];
        const int  t  = targets[b];

        // ---- target fragment: 8 elems as 4x f16 pairs ----
        half2_t tg[4];
        if constexpr (TGT16) {
            const uint4 tv = *reinterpret_cast<const uint4*>(
                tgtb + (((uint32_t)t) << 8) + sub16);
            tg[0] = h2_from_u32(tv.x); tg[1] = h2_from_u32(tv.y);
            tg[2] = h2_from_u32(tv.z); tg[3] = h2_from_u32(tv.w);
        } else {
            const float4 f0 = *reinterpret_cast<const float4*>(
                &target_W[(size_t)t * E_DIM + sub * 8]);
            const float4 f1 = *reinterpret_cast<const float4*>(
                &target_W[(size_t)t * E_DIM + sub * 8 + 4]);
            tg[0] = half2_t{(half_t)f0.x, (half_t)f0.y};
            tg[1] = half2_t{(half_t)f0.z, (half_t)f0.w};
            tg[2] = half2_t{(half_t)f1.x, (half_t)f1.y};
            tg[3] = half2_t{(half_t)f1.z, (half_t)f1.w};
        }

        // 4 independent accumulator chains per score for ILP
        float p0 = 0.f, p1 = 0.f, p2 = 0.f, p3 = 0.f;
        float q0 = 0.f, q1 = 0.f, q2 = 0.f, q3 = 0.f;

        auto row = [&](int idx, float& a0, float& a1, float& a2, float& a3) {
            if constexpr (CTX16) {
                const uint4 rv = *reinterpret_cast<const uint4*>(
                    ctxb + (((uint32_t)idx) << 8) + sub16);
                a0 = dot2acc(h2_from_u32(rv.x), tg[0], a0);
                a1 = dot2acc(h2_from_u32(rv.y), tg[1], a1);
                a2 = dot2acc(h2_from_u32(rv.z), tg[2], a2);
                a3 = dot2acc(h2_from_u32(rv.w), tg[3], a3);
            } else {
                const float4 f0 = *reinterpret_cast<const float4*>(
                    &context_W[(size_t)idx * E_DIM + sub * 8]);
                const float4 f1 = *reinterpret_cast<const float4*>(
                    &context_W[(size_t)idx * E_DIM + sub * 8 + 4]);
                a0 = dot2acc(half2_t{(half_t)f0.x, (half_t)f0.y}, tg[0], a0);
                a1 = dot2acc(half2_t{(half_t)f0.z, (half_t)f0.w}, tg[1], a1);
                a2 = dot2acc(half2_t{(half_t)f1.x, (half_t)f1.y}, tg[2], a2);
                a3 = dot2acc(half2_t{(half_t)f1.z, (half_t)f1.w}, tg[3], a3);
            }
        };

        row(c0.x, p0, p1, p2, p3);
        row(c0.y, p0, p1, p2, p3);
        row(c0.z, p0, p1, p2, p3);
        row(c0.w, p0, p1, p2, p3);
        row(c1.x, p0, p1, p2, p3);
        row(c1.y, p0, p1, p2, p3);
        row(c1.z, p0, p1, p2, p3);
        row(c1.w, p0, p1, p2, p3);
        row(n0,   q0, q1, q2, q3);
        row(n1,   q0, q1, q2, q3);
        row(n2,   q0, q1, q2, q3);

        float pos = (p0 + p1) + (p2 + p3);
        float neg = (q0 + q1) + (q2 + q3);

        // ---- 16-lane butterfly allreduce (per group) ----
        #pragma unroll
        for (int off = 8; off > 0; off >>= 1) {
            pos += __shfl_xor(pos, off, 64);
            neg += __shfl_xor(neg, off, 64);
        }

        // all lanes of the group hold full sums -> no divergence
        wave_sum += log_sigmoid_f(pos * (1.0f / W_CTX)) + log_sigmoid_f(-neg);
    }

    // sum the 4 groups (each group's lanes hold identical wave_sum)
    wave_sum += __shfl_xor(wave_sum, 16, 64);
    wave_sum += __shfl_xor(wave_sum, 32, 64);

    __shared__ float sm[4];
    if (lane == 0) sm[wib] = wave_sum;
    __syncthreads();
    if (threadIdx.x == 0) {
        atomicAdd(out, (sm[0] + sm[1] + sm[2] + sm[3]) * (-1.0f / (float)B_ITEMS));
    }
}

extern "C" void kernel_launch(void* const* d_in, const int* in_sizes, int n_in,
                              void* d_out, int out_size, void* d_ws, size_t ws_size,
                              hipStream_t stream) {
    const int*   targets    = (const int*)  d_in[0];
    const int*   contexts   = (const int*)  d_in[1];
    const int*   negsamples = (const int*)  d_in[2];
    const float* target_W   = (const float*)d_in[3];
    const float* context_W  = (const float*)d_in[4];
    float*       out        = (float*)      d_out;

    // d_out is re-poisoned (0xAA) before every timed replay -> zero it first.
    init_out_kernel<<<1, 64, 0, stream>>>(out);

    uint32_t* ctx16 = (uint32_t*)d_ws;
    uint32_t* tgt16 = (uint32_t*)((char*)d_ws + F16_TABLE_BYTES);
    const int n4 = V_VOCAB * E_DIM / 4;  // float4 chunks per table

    if (ws_size >= 2 * F16_TABLE_BYTES) {
        convert_f16_both_kernel<<<2048, 256, 0, stream>>>(
            context_W, (uint2*)ctx16, target_W, (uint2*)tgt16, n4);
        cbow_kernel<true, true><<<2048, 256, 0, stream>>>(
            targets, contexts, negsamples, target_W, context_W, ctx16, tgt16, out);
    } else if (ws_size >= F16_TABLE_BYTES) {
        convert_f16_both_kernel<<<2048, 256, 0, stream>>>(
            context_W, (uint2*)ctx16, nullptr, (uint2*)nullptr, n4);
        cbow_kernel<true, false><<<2048, 256, 0, stream>>>(
            targets, contexts, negsamples, target_W, context_W, ctx16, nullptr, out);
    } else {
        cbow_kernel<false, false><<<2048, 256, 0, stream>>>(
            targets, contexts, negsamples, target_W, context_W, nullptr, nullptr, out);
    }
}

// Round 4
// 240.356 us; speedup vs baseline: 1.3371x; 1.0024x over previous
//
#include <hip/hip_runtime.h>
#include <math.h>
#include <stdint.h>

// Problem constants (from the reference):
//   B=262144 items, W=8 context window, K=3 negatives, V=100000 vocab, E=128 dim
#define B_ITEMS 262144
#define W_CTX   8
#define K_NEG   3
#define E_DIM   128
#define V_VOCAB 100000

typedef _Float16 half_t;
typedef __attribute__((ext_vector_type(2))) _Float16 half2_t;
typedef __attribute__((ext_vector_type(2))) float   fvec2;

#define CTX_FP8_BYTES ((size_t)V_VOCAB * E_DIM)        // 12.8 MB
#define F16_TABLE_BYTES ((size_t)V_VOCAB * E_DIM * 2)  // 25.6 MB

#if __has_builtin(__builtin_amdgcn_cvt_pk_f32_fp8) && __has_builtin(__builtin_amdgcn_cvt_pk_fp8_f32)
#define HAVE_FP8 1
#else
#define HAVE_FP8 0
#endif

// Numerically stable log-sigmoid: log_sigmoid(x) = min(x,0) - log1p(exp(-|x|))
__device__ __forceinline__ float log_sigmoid_f(float x) {
    return fminf(x, 0.0f) - log1pf(expf(-fabsf(x)));
}

__device__ __forceinline__ half2_t h2_from_u32(uint32_t u) {
    return __builtin_bit_cast(half2_t, u);
}
__device__ __forceinline__ uint32_t u32_from_h2(half2_t h) {
    return __builtin_bit_cast(uint32_t, h);
}

__global__ void init_out_kernel(float* out) {
    if (threadIdx.x == 0 && blockIdx.x == 0) out[0] = 0.0f;
}

#if HAVE_FP8
// context_W f32 -> fp8 e4m3 (HW cvt), target_W f32 -> f16; also zeroes out[0].
__global__ void __launch_bounds__(256) convert_fp8_kernel(
    const float* __restrict__ ctx, uint2* __restrict__ ctx8,
    const float* __restrict__ tgt, uint4* __restrict__ tgt16,
    int n8, float* __restrict__ out)
{
    if (blockIdx.x == 0 && threadIdx.x == 0) out[0] = 0.0f;
    int i = blockIdx.x * blockDim.x + threadIdx.x;
    const int stride = gridDim.x * blockDim.x;
    const float4* c4 = reinterpret_cast<const float4*>(ctx);
    const float4* t4 = reinterpret_cast<const float4*>(tgt);
    for (; i < n8; i += stride) {
        // 8 context elems -> 8 fp8 bytes
        float4 a = c4[2 * i], b = c4[2 * i + 1];
        int lo = __builtin_amdgcn_cvt_pk_fp8_f32(a.x, a.y, 0, false);
        lo     = __builtin_amdgcn_cvt_pk_fp8_f32(a.z, a.w, lo, true);
        int hi = __builtin_amdgcn_cvt_pk_fp8_f32(b.x, b.y, 0, false);
        hi     = __builtin_amdgcn_cvt_pk_fp8_f32(b.z, b.w, hi, true);
        ctx8[i] = make_uint2((uint32_t)lo, (uint32_t)hi);
        // 8 target elems -> 8 f16
        float4 ta = t4[2 * i], tb = t4[2 * i + 1];
        uint4 o;
        o.x = u32_from_h2(half2_t{(half_t)ta.x, (half_t)ta.y});
        o.y = u32_from_h2(half2_t{(half_t)ta.z, (half_t)ta.w});
        o.z = u32_from_h2(half2_t{(half_t)tb.x, (half_t)tb.y});
        o.w = u32_from_h2(half2_t{(half_t)tb.z, (half_t)tb.w});
        tgt16[i] = o;
    }
}
#endif

// Both tables f32 -> f16 (fallback when fp8 builtins unavailable); zeroes out[0].
__global__ void __launch_bounds__(256) convert_f16_both_kernel(
    const float* __restrict__ srcA, uint2* __restrict__ dstA,
    const float* __restrict__ srcB, uint2* __restrict__ dstB,
    int n4, float* __restrict__ out)
{
    if (blockIdx.x == 0 && threadIdx.x == 0) out[0] = 0.0f;
    int i = blockIdx.x * blockDim.x + threadIdx.x;
    const int stride = gridDim.x * blockDim.x;
    const float4* a4 = reinterpret_cast<const float4*>(srcA);
    const float4* b4 = reinterpret_cast<const float4*>(srcB);
    for (; i < n4; i += stride) {
        float4 va = a4[i];
        uint2 oa;
        oa.x = u32_from_h2(half2_t{(half_t)va.x, (half_t)va.y});
        oa.y = u32_from_h2(half2_t{(half_t)va.z, (half_t)va.w});
        dstA[i] = oa;
        float4 vb = b4[i];
        uint2 ob;
        ob.x = u32_from_h2(half2_t{(half_t)vb.x, (half_t)vb.y});
        ob.y = u32_from_h2(half2_t{(half_t)vb.z, (half_t)vb.w});
        dstB[i] = ob;
    }
}

// 4 items per wave-iteration: group g = lanes [16g,16g+15]; lane owns 8 elems.
// MODE 0: f32 gathers (no ws). MODE 1: f16 ctx + f16 tgt (fdot2).
// MODE 2: fp8 ctx (HW cvt_pk_f32_fp8 decode) + f16 tgt.
template <int MODE>
__global__ void __launch_bounds__(256, 8) cbow_kernel(
    const int*      __restrict__ targets,     // [B]
    const int*      __restrict__ contexts,    // [B, W]
    const int*      __restrict__ negsamples,  // [B, K]
    const float*    __restrict__ target_W,    // [V, E] f32
    const float*    __restrict__ context_W,   // [V, E] f32 (MODE 0)
    const char*     __restrict__ ctx8,        // [V, E] fp8 (MODE 2)
    const char*     __restrict__ ctx16,       // [V, E] f16 (MODE 1)
    const char*     __restrict__ tgt16,       // [V, E] f16 (MODE 1/2)
    float*          __restrict__ out)         // [1]
{
    const int lane = threadIdx.x & 63;
    const int wib  = threadIdx.x >> 6;
    const int wid  = blockIdx.x * (blockDim.x >> 6) + wib;
    const int grp  = lane >> 4;          // which item of the quad
    const int sub  = lane & 15;          // 8-elem chunk within the row

    float wave_sum = 0.0f;  // identical across lanes of a group

    // 16384 waves x 4 quads x 4 items = 262144, exact.
    #pragma unroll
    for (int i = 0; i < 4; ++i) {
        const int b = wid * 16 + i * 4 + grp;

        // ---- indices: broadcast loads within each 16-lane group ----
        const int4 c0 = *reinterpret_cast<const int4*>(&contexts[b * W_CTX]);
        const int4 c1 = *reinterpret_cast<const int4*>(&contexts[b * W_CTX + 4]);
        const int  n0 = negsamples[b * K_NEG + 0];
        const int  n1 = negsamples[b * K_NEG + 1];
        const int  n2 = negsamples[b * K_NEG + 2];
        const int  t  = targets[b];

        // ---- target fragment: this lane's 8 elems ----
        float   tf[8];     // MODE 0/2
        half2_t tg[4];     // MODE 1
        if constexpr (MODE == 0) {
            const float4 f0 = *reinterpret_cast<const float4*>(
                &target_W[(size_t)t * E_DIM + sub * 8]);
            const float4 f1 = *reinterpret_cast<const float4*>(
                &target_W[(size_t)t * E_DIM + sub * 8 + 4]);
            tf[0]=f0.x; tf[1]=f0.y; tf[2]=f0.z; tf[3]=f0.w;
            tf[4]=f1.x; tf[5]=f1.y; tf[6]=f1.z; tf[7]=f1.w;
        } else {
            const uint4 tv = *reinterpret_cast<const uint4*>(
                tgt16 + (((uint32_t)t) << 8) + sub * 16);
            if constexpr (MODE == 1) {
                tg[0] = h2_from_u32(tv.x); tg[1] = h2_from_u32(tv.y);
                tg[2] = h2_from_u32(tv.z); tg[3] = h2_from_u32(tv.w);
            } else {
                half2_t h;
                h = h2_from_u32(tv.x); tf[0] = (float)h[0]; tf[1] = (float)h[1];
                h = h2_from_u32(tv.y); tf[2] = (float)h[0]; tf[3] = (float)h[1];
                h = h2_from_u32(tv.z); tf[4] = (float)h[0]; tf[5] = (float)h[1];
                h = h2_from_u32(tv.w); tf[6] = (float)h[0]; tf[7] = (float)h[1];
            }
        }

        // 4 independent accumulator chains per score for ILP
        float p0 = 0.f, p1 = 0.f, p2 = 0.f, p3 = 0.f;
        float q0 = 0.f, q1 = 0.f, q2 = 0.f, q3 = 0.f;

        auto row = [&](int idx, float& a0, float& a1, float& a2, float& a3) {
            if constexpr (MODE == 2) {
#if HAVE_FP8
                const uint2 rv = *reinterpret_cast<const uint2*>(
                    ctx8 + (((uint32_t)idx) << 7) + sub * 8);
                const fvec2 d0 = __builtin_amdgcn_cvt_pk_f32_fp8((int)rv.x, false);
                const fvec2 d1 = __builtin_amdgcn_cvt_pk_f32_fp8((int)rv.x, true);
                const fvec2 d2 = __builtin_amdgcn_cvt_pk_f32_fp8((int)rv.y, false);
                const fvec2 d3 = __builtin_amdgcn_cvt_pk_f32_fp8((int)rv.y, true);
                a0 += d0.x * tf[0] + d0.y * tf[1];
                a1 += d1.x * tf[2] + d1.y * tf[3];
                a2 += d2.x * tf[4] + d2.y * tf[5];
                a3 += d3.x * tf[6] + d3.y * tf[7];
#endif
            } else if constexpr (MODE == 1) {
                const uint4 rv = *reinterpret_cast<const uint4*>(
                    ctx16 + (((uint32_t)idx) << 8) + sub * 16);
                a0 = __builtin_amdgcn_fdot2(h2_from_u32(rv.x), tg[0], a0, false);
                a1 = __builtin_amdgcn_fdot2(h2_from_u32(rv.y), tg[1], a1, false);
                a2 = __builtin_amdgcn_fdot2(h2_from_u32(rv.z), tg[2], a2, false);
                a3 = __builtin_amdgcn_fdot2(h2_from_u32(rv.w), tg[3], a3, false);
            } else {
                const float4 f0 = *reinterpret_cast<const float4*>(
                    &context_W[(size_t)idx * E_DIM + sub * 8]);
                const float4 f1 = *reinterpret_cast<const float4*>(
                    &context_W[(size_t)idx * E_DIM + sub * 8 + 4]);
                a0 += f0.x * tf[0] + f0.y * tf[1];
                a1 += f0.z * tf[2] + f0.w * tf[3];
                a2 += f1.x * tf[4] + f1.y * tf[5];
                a3 += f1.z * tf[6] + f1.w * tf[7];
            }
        };

        row(c0.x, p0, p1, p2, p3);
        row(c0.y, p0, p1, p2, p3);
        row(c0.z, p0, p1, p2, p3);
        row(c0.w, p0, p1, p2, p3);
        row(c1.x, p0, p1, p2, p3);
        row(c1.y, p0, p1, p2, p3);
        row(c1.z, p0, p1, p2, p3);
        row(c1.w, p0, p1, p2, p3);
        row(n0,   q0, q1, q2, q3);
        row(n1,   q0, q1, q2, q3);
        row(n2,   q0, q1, q2, q3);

        float pos = (p0 + p1) + (p2 + p3);
        float neg = (q0 + q1) + (q2 + q3);

        // ---- 16-lane butterfly allreduce (per group) ----
        #pragma unroll
        for (int off = 8; off > 0; off >>= 1) {
            pos += __shfl_xor(pos, off, 64);
            neg += __shfl_xor(neg, off, 64);
        }

        // all lanes of the group hold full sums -> no divergence
        wave_sum += log_sigmoid_f(pos * (1.0f / W_CTX)) + log_sigmoid_f(-neg);
    }

    // sum the 4 groups (each group's lanes hold identical wave_sum)
    wave_sum += __shfl_xor(wave_sum, 16, 64);
    wave_sum += __shfl_xor(wave_sum, 32, 64);

    __shared__ float sm[4];
    if (lane == 0) sm[wib] = wave_sum;
    __syncthreads();
    if (threadIdx.x == 0) {
        atomicAdd(out, (sm[0] + sm[1] + sm[2] + sm[3]) * (-1.0f / (float)B_ITEMS));
    }
}

extern "C" void kernel_launch(void* const* d_in, const int* in_sizes, int n_in,
                              void* d_out, int out_size, void* d_ws, size_t ws_size,
                              hipStream_t stream) {
    const int*   targets    = (const int*)  d_in[0];
    const int*   contexts   = (const int*)  d_in[1];
    const int*   negsamples = (const int*)  d_in[2];
    const float* target_W   = (const float*)d_in[3];
    const float* context_W  = (const float*)d_in[4];
    float*       out        = (float*)      d_out;

    const int blocks = 4096, threads = 256;  // 16384 waves x 16 items

#if HAVE_FP8
    if (ws_size >= CTX_FP8_BYTES + F16_TABLE_BYTES) {
        char* ctx8  = (char*)d_ws;                       // 12.8 MB fp8
        char* tgt16 = (char*)d_ws + CTX_FP8_BYTES;       // 25.6 MB f16
        const int n8 = V_VOCAB * E_DIM / 8;
        convert_fp8_kernel<<<2048, 256, 0, stream>>>(
            context_W, (uint2*)ctx8, target_W, (uint4*)tgt16, n8, out);
        cbow_kernel<2><<<blocks, threads, 0, stream>>>(
            targets, contexts, negsamples, target_W, context_W,
            ctx8, nullptr, tgt16, out);
        return;
    }
#endif
    if (ws_size >= 2 * F16_TABLE_BYTES) {
        char* ctx16 = (char*)d_ws;
        char* tgt16 = (char*)d_ws + F16_TABLE_BYTES;
        const int n4 = V_VOCAB * E_DIM / 4;
        convert_f16_both_kernel<<<2048, 256, 0, stream>>>(
            context_W, (uint2*)ctx16, target_W, (uint2*)tgt16, n4, out);
        cbow_kernel<1><<<blocks, threads, 0, stream>>>(
            targets, contexts, negsamples, target_W, context_W,
            nullptr, ctx16, tgt16, out);
    } else {
        init_out_kernel<<<1, 64, 0, stream>>>(out);
        cbow_kernel<0><<<blocks, threads, 0, stream>>>(
            targets, contexts, negsamples, target_W, context_W,
            nullptr, nullptr, nullptr, out);
    }
}